// Round 6
// baseline (373.551 us; speedup 1.0000x reference)
//
#include <hip/hip_runtime.h>
#include <math.h>

// ---------------------------------------------------------------------------
// gram = x^T x (N=4M, D=10, fp64-accurate reduction) -> fp32 -> LAPACK-
// faithful fp32 ssyevd path (ssytd2 'L' + ssteqr, LAPACK>=3.10 slartg) -> MLP.
// Round 6:
//  * gram: round-5 counters showed VGPR_Count=52 for ~85 live floats ->
//    acc[55] was scratch-spilled all along (96us, VALUBusy 10%). Fix:
//    __launch_bounds__(256,4) (cap 128 VGPR) + global_load_lds width-16 into
//    wave-private LDS tiles (no staging regs, no __syncthreads in loop).
//  * eig: all control conditions come from float compares the compiler can't
//    prove uniform -> exec-mask control flow everywhere. Route every branch
//    condition through readfirstlane (u_cond) -> scalar branches. Bit-identical
//    values; arithmetic order unchanged from passing rounds 2-5.
// ---------------------------------------------------------------------------

#define BLK2 256
#define GRID2 1024
#define WTILE 320                 // float4 per wave-tile (= 64 rows)
#define NWAVES (GRID2 * 4)

typedef const __attribute__((address_space(1))) void* gas_ptr;
typedef __attribute__((address_space(3))) void* las_ptr;

__device__ __forceinline__ void load_lds16(const void* g, void* l) {
  __builtin_amdgcn_global_load_lds((gas_ptr)g, (las_ptr)l, 16, 0, 0);
}

__global__ void zero_ws_kernel(double* __restrict__ g) {
  int t = threadIdx.x;
  if (t < 220) g[t] = 0.0;
}

__global__ __launch_bounds__(BLK2, 4) void gram_kernel(const float4* __restrict__ x4,
                                                       double* __restrict__ g,
                                                       int nf4) {
  __shared__ float4 tile[4 * WTILE];  // wave-private 5KB regions
  float acc[55];
#pragma unroll
  for (int k = 0; k < 55; k++) acc[k] = 0.0f;

  const int lane = threadIdx.x & 63;
  const int wv = threadIdx.x >> 6;
  const int gwave = blockIdx.x * 4 + wv;
  const int nwt = nf4 / WTILE;  // 31250 exactly for N=4M (no tail)
  float4* lbase = &tile[wv * WTILE];

  for (int t = gwave; t < nwt; t += NWAVES) {
    const float4* gsrc = x4 + (size_t)t * WTILE + lane;
#pragma unroll
    for (int k = 0; k < 5; k++) load_lds16(gsrc + k * 64, lbase + k * 64);
    __builtin_amdgcn_s_waitcnt(0);  // drain global_load_lds before ds_read
    float4 q0 = lbase[lane * 5 + 0];
    float4 q1 = lbase[lane * 5 + 1];
    float4 q2 = lbase[lane * 5 + 2];
    float4 q3 = lbase[lane * 5 + 3];
    float4 q4 = lbase[lane * 5 + 4];
    float v[20] = {q0.x, q0.y, q0.z, q0.w, q1.x, q1.y, q1.z, q1.w,
                   q2.x, q2.y, q2.z, q2.w, q3.x, q3.y, q3.z, q3.w,
                   q4.x, q4.y, q4.z, q4.w};
    int k = 0;
#pragma unroll
    for (int i = 0; i < 10; i++) {
#pragma unroll
      for (int j = 0; j <= i; j++) {
        acc[k] += v[i] * v[j] + v[10 + i] * v[10 + j];
        k++;
      }
    }
  }

  __shared__ double sred[4][55];
#pragma unroll
  for (int k = 0; k < 55; k++) {
    double d = (double)acc[k];
#pragma unroll
    for (int off = 32; off > 0; off >>= 1) d += __shfl_down(d, off, 64);
    if (lane == 0) sred[wv][k] = d;
  }
  __syncthreads();
  double* gr = g + 55 * (blockIdx.x & 3);  // 4 replicas
  if (threadIdx.x < 55) {
    double s = sred[0][threadIdx.x] + sred[1][threadIdx.x] +
               sred[2][threadIdx.x] + sred[3][threadIdx.x];
    atomicAdd(&gr[threadIdx.x], s);
  }
}

// ------------------------- LAPACK helpers (fp32) ---------------------------

// wave-uniform condition -> SGPR (values are identical across lanes)
__device__ __forceinline__ int u_cond(bool b) {
  return __builtin_amdgcn_readfirstlane(b ? 1 : 0);
}

__device__ __forceinline__ float sf_sign(float a, float b) {
  return (b >= 0.0f) ? fabsf(a) : -fabsf(a);
}

__device__ __forceinline__ float slapy2(float x, float y) {
  float xa = fabsf(x), ya = fabsf(y);
  float w = fmaxf(xa, ya), z = fminf(xa, ya);
  if (u_cond(z == 0.0f)) return w;
  float q = z / w;
  return w * sqrtf(1.0f + q * q);
}

// LAPACK >= 3.10 slartg, scalarized control
__device__ __forceinline__ void slartg(float f, float g, float* c, float* s, float* r) {
  int cls = __builtin_amdgcn_readfirstlane(g == 0.0f ? 0 : (f == 0.0f ? 1 : 2));
  if (cls == 0) {
    *c = 1.0f; *s = 0.0f; *r = f;
  } else if (cls == 1) {
    *c = 0.0f; *s = sf_sign(1.0f, g); *r = fabsf(g);
  } else {
    float d = sqrtf(f * f + g * g);
    *c = fabsf(f) / d;
    float rr = sf_sign(d, f);
    *s = g / rr;
    *r = rr;
  }
}

__device__ __forceinline__ void slaev2(float a, float b, float c,
                                       float* rt1, float* rt2, float* cs1, float* sn1) {
  float sm = a + c;
  float df = a - c;
  float adf = fabsf(df);
  float tb = b + b;
  float ab = fabsf(tb);
  float acmx, acmn;
  if (u_cond(fabsf(a) > fabsf(c))) { acmx = a; acmn = c; } else { acmx = c; acmn = a; }
  float rt;
  if (u_cond(adf > ab))      { float t = ab / adf; rt = adf * sqrtf(1.0f + t * t); }
  else if (u_cond(adf < ab)) { float t = adf / ab; rt = ab * sqrtf(1.0f + t * t); }
  else                       { rt = ab * sqrtf(2.0f); }
  int sgn1;
  int smc = __builtin_amdgcn_readfirstlane(sm < 0.0f ? 0 : (sm > 0.0f ? 1 : 2));
  if (smc == 0) {
    *rt1 = 0.5f * (sm - rt); sgn1 = -1;
    *rt2 = (acmx / *rt1) * acmn - (b / *rt1) * b;
  } else if (smc == 1) {
    *rt1 = 0.5f * (sm + rt); sgn1 = 1;
    *rt2 = (acmx / *rt1) * acmn - (b / *rt1) * b;
  } else {
    *rt1 = 0.5f * rt; *rt2 = -0.5f * rt; sgn1 = 1;
  }
  int sgn2;
  float cs;
  if (u_cond(df >= 0.0f)) { cs = df + rt; sgn2 = 1; } else { cs = df - rt; sgn2 = -1; }
  float acs = fabsf(cs);
  if (u_cond(acs > ab)) {
    float ct = -tb / cs;
    *sn1 = 1.0f / sqrtf(1.0f + ct * ct);
    *cs1 = ct * (*sn1);
  } else {
    if (u_cond(ab == 0.0f)) { *cs1 = 1.0f; *sn1 = 0.0f; }
    else {
      float tn = -cs / tb;
      *cs1 = 1.0f / sqrtf(1.0f + tn * tn);
      *sn1 = tn * (*cs1);
    }
  }
  if (sgn1 == sgn2) { float tn = *cs1; *cs1 = -(*sn1); *sn1 = tn; }
}

// 10-way register select / masked write (runtime idx0, 0-based); branch-free.
__device__ __forceinline__ float sel10(const float* a, int idx0) {
  float v = 0.0f;
#pragma unroll
  for (int k = 0; k < 10; k++) v = (k == idx0) ? a[k] : v;
  return v;
}
__device__ __forceinline__ void put10(float* a, int idx0, float v) {
#pragma unroll
  for (int k = 0; k < 10; k++) a[k] = (k == idx0) ? v : a[k];
}

// static 1-based access macros (indices must be compile-time constants)
#define A_(r, c) Am[((r)-1) * 10 + ((c)-1)]
#define Z_(r, c) Zm[((r)-1) * 10 + ((c)-1)]
#define D_(i) dv[(i)-1]
#define E_(i) ev[(i)-1]
#define TAUV(i) tauv[(i)-1]
#define WV(i) wvv[(i)-1]

__global__ __launch_bounds__(64, 1) void eig_mlp_kernel(
    const double* __restrict__ g,
    const float* __restrict__ W1,
    const float* __restrict__ b1,
    const float* __restrict__ W2,
    const float* __restrict__ b2,
    float* __restrict__ out) {
  if (blockIdx.x != 0) return;
  const int lane = threadIdx.x;
  const int n = 10;
  float Am[100], Zm[100];
  float dv[10], ev[10], tauv[10], wvv[10], csv[10], snv[10];

  // load gram (4 replicas summed in fp64), round to fp32 — uniform on all lanes
  {
    int k = 0;
#pragma unroll
    for (int i = 0; i < 10; i++)
#pragma unroll
      for (int j = 0; j <= i; j++) {
        double v = g[k] + g[55 + k] + g[110 + k] + g[165 + k];
        float f = (float)v;
        Am[i * 10 + j] = f;
        Am[j * 10 + i] = f;
        k++;
      }
  }

  // -------- ssytd2 (UPLO='L'), static, register-resident, scalar control ---
#pragma unroll
  for (int i = 1; i <= n - 1; i++) {
    const int nmi = n - i;
    float alpha = A_(i + 1, i);
    float taui = 0.0f;
    if (nmi > 1) {
      float ss = 0.0f;
#pragma unroll
      for (int r = i + 2; r <= n; r++) { float t = A_(r, i); ss += t * t; }
      float xnorm = sqrtf(ss);
      if (u_cond(xnorm != 0.0f)) {
        float beta = -sf_sign(slapy2(alpha, xnorm), alpha);
        taui = (beta - alpha) / beta;
        float sc = 1.0f / (alpha - beta);
#pragma unroll
        for (int r = i + 2; r <= n; r++) A_(r, i) *= sc;
        alpha = beta;
      }
    }
    E_(i) = alpha;
    A_(i + 1, i) = alpha;
    if (u_cond(taui != 0.0f)) {
      A_(i + 1, i) = 1.0f;
#pragma unroll
      for (int r = i + 1; r <= n; r++) {
        float s = 0.0f;
#pragma unroll
        for (int c = i + 1; c <= n; c++) {
          float arc = (r >= c) ? A_(r, c) : A_(c, r);
          s += arc * A_(c, i);
        }
        WV(r) = taui * s;
      }
      float dot = 0.0f;
#pragma unroll
      for (int r = i + 1; r <= n; r++) dot += WV(r) * A_(r, i);
      float al2 = -0.5f * taui * dot;
#pragma unroll
      for (int r = i + 1; r <= n; r++) WV(r) += al2 * A_(r, i);
#pragma unroll
      for (int c = i + 1; c <= n; c++)
#pragma unroll
        for (int r = c; r <= n; r++)
          A_(r, c) -= A_(r, i) * WV(c) + WV(r) * A_(c, i);
      A_(i + 1, i) = E_(i);
    }
    D_(i) = A_(i, i);
    TAUV(i) = taui;
  }
  D_(n) = A_(n, n);

  // -------- form Q0 = H(1)...H(n-1), static, scalar control --------
#pragma unroll
  for (int r = 1; r <= n; r++)
#pragma unroll
    for (int c = 1; c <= n; c++) Z_(r, c) = (r == c) ? 1.0f : 0.0f;
#pragma unroll
  for (int i = n - 1; i >= 1; i--) {
    float taui = TAUV(i);
    if (u_cond(taui != 0.0f)) {
#pragma unroll
      for (int c = 1; c <= n; c++) {
        float t = Z_(i + 1, c);
#pragma unroll
        for (int r = i + 2; r <= n; r++) t += A_(r, i) * Z_(r, c);
        t *= taui;
        Z_(i + 1, c) -= t;
#pragma unroll
        for (int r = i + 2; r <= n; r++) Z_(r, c) -= A_(r, i) * t;
      }
    }
  }

  // -------- distribute Z rows: lane r holds row r as z[0..9] --------
  const int r_own = (lane < 10) ? lane : 0;
  float z[10];
#pragma unroll
  for (int k = 0; k < 10; k++) {
    float v = Zm[0 * 10 + k];
#pragma unroll
    for (int rr = 1; rr < 10; rr++) v = (r_own == rr) ? Zm[rr * 10 + k] : v;
    z[k] = v;
  }

  // -------- ssteqr ('V'); scalar control, static guarded sweeps ----------
  const float eps = 5.9604644775390625e-08f;      // 2^-24
  const float eps2 = eps * eps;
  const float safmin = 1.17549435082228751e-38f;  // 2^-126
  const int nmaxit = n * 30;
  int jtot = 0;
  int l1 = 1;
  int guard = 0;

  while (l1 <= n && guard++ < 2000) {
    if (l1 > 1) put10(ev, l1 - 2, 0.0f);  // E_(l1-1) = 0
    int m = n;
#pragma unroll
    for (int k = 1; k <= n - 1; k++) {
      if (m == n && k >= l1) {
        float tst = fabsf(ev[k - 1]);
        int cls = __builtin_amdgcn_readfirstlane(
            tst == 0.0f
                ? 1
                : (tst <= (sqrtf(fabsf(dv[k - 1])) * sqrtf(fabsf(dv[k]))) * eps ? 2 : 0));
        if (cls) {
          if (cls == 2) ev[k - 1] = 0.0f;
          m = k;
        }
      }
    }
    int l = l1, lsv = l, lend = m, lendsv = m;
    l1 = m + 1;
    if (lend == l) continue;
    if (u_cond(fabsf(sel10(dv, lend - 1)) < fabsf(sel10(dv, l - 1)))) { lend = lsv; l = lendsv; }

    if (lend > l) {
      // ---------------- QL iteration ----------------
      for (;;) {
        if (guard++ > 4000) break;
        int m2 = lend;
        if (l != lend) {
          int fnd = 0;
#pragma unroll
          for (int k = 1; k <= n - 1; k++) {
            if (!fnd && k >= l && k <= lend - 1) {
              float e = ev[k - 1];
              if (u_cond(e * e <= (eps2 * fabsf(dv[k - 1])) * fabsf(dv[k]) + safmin)) {
                m2 = k; fnd = 1;
              }
            }
          }
        }
        if (m2 < lend) put10(ev, m2 - 1, 0.0f);
        float p = sel10(dv, l - 1);
        if (m2 == l) {  // eigenvalue found
          put10(dv, l - 1, p);
          l = l + 1;
          if (l <= lend) continue;
          break;
        }
        if (m2 == l + 1) {  // 2x2 block; 0-based cols (l, l-1)
          float rt1, rt2, c2, s2;
          slaev2(sel10(dv, l - 1), sel10(ev, l - 1), sel10(dv, l), &rt1, &rt2, &c2, &s2);
          float a = sel10(z, l);
          float b = sel10(z, l - 1);
          put10(z, l, c2 * a - s2 * b);
          put10(z, l - 1, s2 * a + c2 * b);
          put10(dv, l - 1, rt1);
          put10(dv, l, rt2);
          put10(ev, l - 1, 0.0f);
          l = l + 2;
          if (l <= lend) continue;
          break;
        }
        if (jtot == nmaxit) break;
        jtot++;
        float El = sel10(ev, l - 1);
        float gg = (sel10(dv, l) - p) / (2.0f * El);
        float rr = slapy2(gg, 1.0f);
        gg = sel10(dv, m2 - 1) - p + (El / (gg + sf_sign(rr, gg)));
        float s = 1.0f, c = 1.0f;
        p = 0.0f;
#pragma unroll
        for (int i = n - 1; i >= 1; i--) {
          if (i <= m2 - 1 && i >= l) {
            float e = ev[i - 1];
            float f = s * e, b = c * e;
            slartg(gg, f, &c, &s, &rr);
            if (i != m2 - 1) ev[i] = rr;  // E_(i+1), static
            gg = dv[i] - p;               // D_(i+1)
            rr = (dv[i - 1] - gg) * s + 2.0f * c * b;
            p = s * rr;
            dv[i] = gg + p;
            gg = c * rr - b;
            csv[i - 1] = c;
            snv[i - 1] = -s;
          }
        }
        // apply rotations (slasr 'B'): descending j, 0-based cols (j, j-1)
        {
          float a = sel10(z, m2 - 1);
#pragma unroll
          for (int j = n - 1; j >= 1; j--) {
            if (j <= m2 - 1 && j >= l) {
              float cj = csv[j - 1], sj = snv[j - 1];
              float b = z[j - 1];
              z[j] = cj * a - sj * b;
              a = sj * a + cj * b;
            }
          }
          put10(z, l - 1, a);
        }
        put10(dv, l - 1, sel10(dv, l - 1) - p);
        put10(ev, l - 1, gg);
      }
    } else {
      // ---------------- QR iteration ----------------
      for (;;) {
        if (guard++ > 4000) break;
        int m2 = lend;
        if (l != lend) {
          int fnd = 0;
#pragma unroll
          for (int k = n; k >= 2; k--) {
            if (!fnd && k <= l && k >= lend + 1) {
              float e = ev[k - 2];
              if (u_cond(e * e <= (eps2 * fabsf(dv[k - 1])) * fabsf(dv[k - 2]) + safmin)) {
                m2 = k; fnd = 1;
              }
            }
          }
        }
        if (m2 > lend) put10(ev, m2 - 2, 0.0f);  // E_(m2-1) = 0
        float p = sel10(dv, l - 1);
        if (m2 == l) {  // eigenvalue found
          put10(dv, l - 1, p);
          l = l - 1;
          if (l >= lend) continue;
          break;
        }
        if (m2 == l - 1) {  // 2x2 block; 0-based cols (l-1, l-2)
          float rt1, rt2, c2, s2;
          slaev2(sel10(dv, l - 2), sel10(ev, l - 2), sel10(dv, l - 1), &rt1, &rt2, &c2, &s2);
          float a = sel10(z, l - 1);
          float b = sel10(z, l - 2);
          put10(z, l - 1, c2 * a - s2 * b);
          put10(z, l - 2, s2 * a + c2 * b);
          put10(dv, l - 2, rt1);
          put10(dv, l - 1, rt2);
          put10(ev, l - 2, 0.0f);
          l = l - 2;
          if (l >= lend) continue;
          break;
        }
        if (jtot == nmaxit) break;
        jtot++;
        float El1 = sel10(ev, l - 2);  // E_(l-1)
        float gg = (sel10(dv, l - 2) - p) / (2.0f * El1);
        float rr = slapy2(gg, 1.0f);
        gg = sel10(dv, m2 - 1) - p + (El1 / (gg + sf_sign(rr, gg)));
        float s = 1.0f, c = 1.0f;
        p = 0.0f;
#pragma unroll
        for (int i = 1; i <= n - 1; i++) {
          if (i >= m2 && i <= l - 1) {
            float e = ev[i - 1];
            float f = s * e, b = c * e;
            slartg(gg, f, &c, &s, &rr);
            if (i >= 2) {
              if (i != m2) ev[i - 2] = rr;  // E_(i-1), static
            }
            gg = dv[i - 1] - p;  // D_(i)
            rr = (dv[i] - gg) * s + 2.0f * c * b;
            p = s * rr;
            dv[i - 1] = gg + p;
            gg = c * rr - b;
            csv[i - 1] = c;
            snv[i - 1] = s;
          }
        }
        // apply rotations (slasr 'F'): ascending j, 0-based cols (j, j-1)
        {
          float carry = sel10(z, m2 - 1);
#pragma unroll
          for (int j = 1; j <= n - 1; j++) {
            if (j >= m2 && j <= l - 1) {
              float cj = csv[j - 1], sj = snv[j - 1];
              float t = z[j];
              z[j - 1] = sj * t + cj * carry;
              carry = cj * t - sj * carry;
            }
          }
          put10(z, l - 1, carry);
        }
        put10(dv, l - 1, sel10(dv, l - 1) - p);
        put10(ev, l - 2, gg);  // E_(l-1)
      }
    }
  }

  // -------- selection sort ascending (as in ssteqr), scalar control -------
  for (int ii = 2; ii <= n; ii++) {
    int i = ii - 1;
    int k = i;
    float p = sel10(dv, i - 1);
    for (int j = ii; j <= n; j++) {
      float dj = sel10(dv, j - 1);
      if (u_cond(dj < p)) { k = j; p = dj; }
    }
    if (k != i) {
      float di = sel10(dv, i - 1);
      put10(dv, k - 1, di);
      put10(dv, i - 1, p);
      float a = sel10(z, i - 1), b = sel10(z, k - 1);
      put10(z, i - 1, b);
      put10(z, k - 1, a);
    }
  }

  // -------- MLP per lane (lane r computes output row r) --------
  if (lane < 10) {
    double o = (double)b2[0];
#pragma unroll
    for (int h = 0; h < 16; h++) {
      double sgm = (double)b1[h];
#pragma unroll
      for (int k = 0; k < 10; k++) sgm += (double)z[k] * (double)W1[h * 10 + k];
      if (sgm > 0.0) o += sgm * (double)W2[h];
    }
    double sig = 1.0 / (1.0 + exp(-o));
    out[lane] = (float)(0.5 * (sig + 1.0));
  }
}

extern "C" void kernel_launch(void* const* d_in, const int* in_sizes, int n_in,
                              void* d_out, int out_size, void* d_ws, size_t ws_size,
                              hipStream_t stream) {
  const float* x  = (const float*)d_in[0];
  const float* W1 = (const float*)d_in[1];
  const float* b1 = (const float*)d_in[2];
  const float* W2 = (const float*)d_in[3];
  const float* b2 = (const float*)d_in[4];
  double* g = (double*)d_ws;
  float* out = (float*)d_out;

  int nf4 = in_sizes[0] / 4;  // 10M float4 (divisible by WTILE=320 for N=4M)

  zero_ws_kernel<<<1, 256, 0, stream>>>(g);
  gram_kernel<<<GRID2, BLK2, 0, stream>>>((const float4*)x, g, nf4);
  eig_mlp_kernel<<<1, 64, 0, stream>>>(g, W1, b1, W2, b2, out);
}